// Round 4
// baseline (908.103 us; speedup 1.0000x reference)
//
#include <hip/hip_runtime.h>
#include <hip/hip_cooperative_groups.h>
#include <cmath>

namespace cg = cooperative_groups;

namespace {
constexpr int NELEM  = 50000;
constexpr int NSYN   = 500;
constexpr int NQ4    = 125;     // NSYN/4
constexpr int NB     = 256;     // grid blocks (1 per CU, co-resident)
constexpr int T      = 1024;    // threads per block
constexpr int SBLK   = 49;      // scan blocks: 49*1024 = 50176 >= NELEM
constexpr int SLOTS  = SBLK * T;
constexpr int NCHUNK = SLOTS / 64;          // 784
constexpr int CMAXC  = (NELEM - 1) / 64;    // 781
constexpr int MAXSEG = 2048;
constexpr int NGRP   = NELEM / 8;           // 6250 row-groups of 8
constexpr double DELTA_D = 1.0e-3;
constexpr double THETA_D = 1.0;
constexpr float  DECAY_F = 0.90483741803595957311f;  // float32(exp(-1/10))
}

struct WS {
    double2 pq[SLOTS];            // (P,Q) entering element i
    double  gAm[64], gAg[64], gAi[64];   // block aggregates, round 1
    double  gEm[64], gEg[64], gEi[64];   // block exclusive entries, round 1
    double  gPp[64], gPq[64];            // block aggregates, round 2
    double  gEp[64], gEq[64];            // block exclusive entries, round 2
    double  gmaxR[NCHUNK];               // per-64-chunk slack-inflated max R
    double  gbndQ[MAXSEG];
    int     gbnd[MAXSEG];
    int     gnseg;
    int     pad;
    float   swv[SLOTS];
    float   iwv[SLOTS];
};

__global__ __launch_bounds__(1024, 4) void k_fused(
    const float* __restrict__ spikes,
    const float* __restrict__ w,
    const float* __restrict__ vrev,
    float* __restrict__ out,
    WS* __restrict__ ws)
{
    cg::grid_group grid = cg::this_grid();
    const int tid  = threadIdx.x;
    const int lane = tid & 63;
    const int wv   = tid >> 6;
    const int blk  = blockIdx.x;
    const int gwave = blk * 16 + wv;            // 0..4095

    __shared__ double s_a[16], s_b[16], s_c[16];

    // ================= Phase R: row dots (all 256 blocks) =================
    {
        const float4* __restrict__ w4 = reinterpret_cast<const float4*>(w);
        const float4* __restrict__ r4 = reinterpret_cast<const float4*>(vrev);
        const int j1 = lane;
        const int j2 = lane + 64;
        const bool has2 = (j2 < NQ4);           // lanes 0..60
        float4 a1 = w4[j1], r1 = r4[j1];
        float4 aw1 = make_float4(fabsf(a1.x), fabsf(a1.y), fabsf(a1.z), fabsf(a1.w));
        float4 ar1 = make_float4(aw1.x * r1.x, aw1.y * r1.y, aw1.z * r1.z, aw1.w * r1.w);
        float4 aw2 = make_float4(0.f, 0.f, 0.f, 0.f), ar2 = aw2;
        if (has2) {
            float4 a2 = w4[j2], r2 = r4[j2];
            aw2 = make_float4(fabsf(a2.x), fabsf(a2.y), fabsf(a2.z), fabsf(a2.w));
            ar2 = make_float4(aw2.x * r2.x, aw2.y * r2.y, aw2.z * r2.z, aw2.w * r2.w);
        }
        for (int rg = gwave; rg < NGRP; rg += 4096) {
            const int row0 = rg * 8;
            float sp[8], ip[8];
#pragma unroll
            for (int r = 0; r < 8; ++r) {
                const float4* __restrict__ srow =
                    reinterpret_cast<const float4*>(spikes + (size_t)(row0 + r) * NSYN);
                float4 s1 = srow[j1];
                float a = s1.x * aw1.x + s1.y * aw1.y + s1.z * aw1.z + s1.w * aw1.w;
                float b = s1.x * ar1.x + s1.y * ar1.y + s1.z * ar1.z + s1.w * ar1.w;
                if (has2) {
                    float4 s2 = srow[j2];
                    a += s2.x * aw2.x + s2.y * aw2.y + s2.z * aw2.z + s2.w * aw2.w;
                    b += s2.x * ar2.x + s2.y * ar2.y + s2.z * ar2.z + s2.w * ar2.w;
                }
                sp[r] = a; ip[r] = b;
            }
#pragma unroll
            for (int d = 32; d > 0; d >>= 1) {
#pragma unroll
                for (int r = 0; r < 8; ++r) {
                    sp[r] += __shfl_xor(sp[r], d);
                    ip[r] += __shfl_xor(ip[r], d);
                }
            }
            if (lane == 0) {
                *reinterpret_cast<float4*>(ws->swv + row0)     = make_float4(sp[0], sp[1], sp[2], sp[3]);
                *reinterpret_cast<float4*>(ws->swv + row0 + 4) = make_float4(sp[4], sp[5], sp[6], sp[7]);
                *reinterpret_cast<float4*>(ws->iwv + row0)     = make_float4(ip[0], ip[1], ip[2], ip[3]);
                *reinterpret_cast<float4*>(ws->iwv + row0 + 4) = make_float4(ip[4], ip[5], ip[6], ip[7]);
            }
        }
    }
    __threadfence();
    grid.sync();   // [1]

    const int  idx    = blk * T + tid;
    const bool inScan = (blk < SBLK);
    const bool live   = inScan && (idx < NELEM);
    const double decay = (double)DECAY_F;

    // ============ Round 1: exclusive scan of affine (m, g, i) ============
    // element op: x -> decay*x + decay*s   (state = exp-trace entering elem)
    double m_in = 1.0, g_in = 0.0, i_in = 0.0;
    if (inScan) {
        double s = live ? (double)ws->swv[idx] : 0.0;
        double t = live ? (double)ws->iwv[idx] : 0.0;
        m_in = live ? decay : 1.0;
        g_in = live ? s * decay : 0.0;
        i_in = live ? t * decay : 0.0;
#pragma unroll
        for (int d = 1; d < 64; d <<= 1) {       // wave inclusive scan
            double pm = __shfl_up(m_in, d);
            double pg = __shfl_up(g_in, d);
            double pi = __shfl_up(i_in, d);
            if (lane >= d) {
                g_in = m_in * pg + g_in;
                i_in = m_in * pi + i_in;
                m_in = pm * m_in;
            }
        }
        if (lane == 63) { s_a[wv] = m_in; s_b[wv] = g_in; s_c[wv] = i_in; }
    }
    __syncthreads();
    if (inScan && wv == 0) {                     // scan 16 wave aggregates
        double wm = (lane < 16) ? s_a[lane] : 1.0;
        double wg = (lane < 16) ? s_b[lane] : 0.0;
        double wi = (lane < 16) ? s_c[lane] : 0.0;
#pragma unroll
        for (int d = 1; d < 16; d <<= 1) {
            double pm = __shfl_up(wm, d);
            double pg = __shfl_up(wg, d);
            double pi = __shfl_up(wi, d);
            if (lane >= d) {
                wg = wm * pg + wg;
                wi = wm * pi + wi;
                wm = pm * wm;
            }
        }
        if (lane < 16) { s_a[lane] = wm; s_b[lane] = wg; s_c[lane] = wi; }
        if (lane == 15) { ws->gAm[blk] = wm; ws->gAg[blk] = wg; ws->gAi[blk] = wi; }
    }
    __threadfence();
    grid.sync();   // [2]

    if (blk == 0 && wv == 0) {                   // grid scan of 49 block aggs
        double am = (lane < SBLK) ? ws->gAm[lane] : 1.0;
        double ag = (lane < SBLK) ? ws->gAg[lane] : 0.0;
        double ai = (lane < SBLK) ? ws->gAi[lane] : 0.0;
#pragma unroll
        for (int d = 1; d < 64; d <<= 1) {
            double pm = __shfl_up(am, d);
            double pg = __shfl_up(ag, d);
            double pi = __shfl_up(ai, d);
            if (lane >= d) {
                ag = am * pg + ag;
                ai = am * pi + ai;
                am = pm * am;
            }
        }
        double em = __shfl_up(am, 1), eg = __shfl_up(ag, 1), ei = __shfl_up(ai, 1);
        if (lane == 0) { em = 1.0; eg = 0.0; ei = 0.0; }
        if (lane < SBLK) { ws->gEm[lane] = em; ws->gEg[lane] = eg; ws->gEi[lane] = ei; }
    }
    __threadfence();
    grid.sync();   // [3]

    // apply: exclusive prefix entering element idx  (x0 = 0 -> E = g-component)
    double Eg = 0.0, Ei = 0.0;
    if (inScan) {
        double em = __shfl_up(m_in, 1), eg = __shfl_up(g_in, 1), ei = __shfl_up(i_in, 1);
        if (lane == 0) { em = 1.0; eg = 0.0; ei = 0.0; }
        if (wv > 0) {
            double qm = s_a[wv - 1], qg = s_b[wv - 1], qi = s_c[wv - 1];
            eg = em * qg + eg;
            ei = em * qi + ei;
            em = qm * em;
        }
        {
            double qm = ws->gEm[blk], qg = ws->gEg[blk], qi = ws->gEi[blk];
            eg = em * qg + eg;
            ei = em * qi + ei;
            em = qm * em;
        }
        Eg = eg; Ei = ei;
    }
    __syncthreads();   // round-1 LDS reads done before round-2 overwrites

    // ============ Round 2: exclusive scan of (p, q) ============
    // element op e = (om, bb/om); compose(prev,cur) = (p1*p2, q1 + q2/p1)
    double p_in = 1.0, q_in = 0.0;
    if (inScan) {
        if (live) {
            double aa = DELTA_D * (1.0 + Eg);
            double om = 1.0 - aa;
            p_in = om;
            q_in = (DELTA_D * Ei) / om;
        }
#pragma unroll
        for (int d = 1; d < 64; d <<= 1) {
            double pp = __shfl_up(p_in, d);
            double pq = __shfl_up(q_in, d);
            if (lane >= d) {
                q_in = pq + q_in / pp;
                p_in = pp * p_in;
            }
        }
        if (lane == 63) { s_a[wv] = p_in; s_b[wv] = q_in; }
    }
    __syncthreads();
    if (inScan && wv == 0) {
        double wp = (lane < 16) ? s_a[lane] : 1.0;
        double wq = (lane < 16) ? s_b[lane] : 0.0;
#pragma unroll
        for (int d = 1; d < 16; d <<= 1) {
            double pp = __shfl_up(wp, d);
            double pq = __shfl_up(wq, d);
            if (lane >= d) {
                wq = pq + wq / pp;
                wp = pp * wp;
            }
        }
        if (lane < 16) { s_a[lane] = wp; s_b[lane] = wq; }
        if (lane == 15) { ws->gPp[blk] = wp; ws->gPq[blk] = wq; }
    }
    __threadfence();
    grid.sync();   // [4]

    if (blk == 0 && wv == 0) {
        double ap = (lane < SBLK) ? ws->gPp[lane] : 1.0;
        double aq = (lane < SBLK) ? ws->gPq[lane] : 0.0;
#pragma unroll
        for (int d = 1; d < 64; d <<= 1) {
            double pp = __shfl_up(ap, d);
            double pq = __shfl_up(aq, d);
            if (lane >= d) {
                aq = pq + aq / pp;
                ap = pp * ap;
            }
        }
        double ep = __shfl_up(ap, 1), eq = __shfl_up(aq, 1);
        if (lane == 0) { ep = 1.0; eq = 0.0; }
        if (lane < SBLK) { ws->gEp[lane] = ep; ws->gEq[lane] = eq; }
    }
    __threadfence();
    grid.sync();   // [5]

    // apply: (P, Q) entering element idx; store pq; per-chunk max R
    double P = 1.0, Q = 0.0;
    if (inScan) {
        double ep = __shfl_up(p_in, 1), eq = __shfl_up(q_in, 1);
        if (lane == 0) { ep = 1.0; eq = 0.0; }
        if (wv > 0) {
            double ap = s_a[wv - 1], aq = s_b[wv - 1];
            eq = aq + eq / ap;
            ep = ap * ep;
        }
        {
            double ap = ws->gEp[blk], aq = ws->gEq[blk];
            eq = aq + eq / ap;
            ep = ap * ep;
        }
        P = ep; Q = eq;
        ws->pq[idx] = make_double2(P, Q);
        double R = -1.0e308;
        if (live) {
            double tp = THETA_D / P;
            R = (Q - tp) + 1.0e-12 * (fabs(Q) + tp);   // conservative slack
        }
#pragma unroll
        for (int d = 32; d > 0; d >>= 1) R = fmax(R, __shfl_xor(R, d));
        if (lane == 0) ws->gmaxR[idx >> 6] = R;
    }
    __threadfence();
    grid.sync();   // [6]

    // ================= Phase S: serial segment search (1 wave) =================
    if (blk == 0 && wv == 0) {
        int nseg = 1;
        if (lane == 0) { ws->gbnd[0] = 0; ws->gbndQ[0] = 0.0; }
        double Qr = 0.0;
        int pos = 1;
        while (pos < NELEM && nseg < MAXSEG) {
            int c = pos >> 6;
            int i0 = -1;
            while (true) {
                // first chunk cc >= c whose (slack-inflated) maxR can cross Qr
                int cf = -1;
                for (int cb = c; cb <= CMAXC; cb += 64) {
                    int cc = cb + lane;
                    bool qy = (cc <= CMAXC) && (ws->gmaxR[cc] >= Qr);
                    unsigned long long m = __ballot(qy);
                    if (m) { cf = cb + __builtin_ctzll(m); break; }
                }
                if (cf < 0) break;
                // exact probe of chunk cf (mask i >= pos)
                int i = (cf << 6) + lane;
                bool valid = (i >= pos) && (i < NELEM);
                double v = -1.0;
                if (valid) { double2 pl = ws->pq[i]; v = pl.x * (pl.y - Qr); }
                unsigned long long m2 = __ballot(valid && (v >= THETA_D));
                if (m2) { i0 = (cf << 6) + __builtin_ctzll(m2); break; }
                c = cf + 1;                 // slack false positive
                if (c > CMAXC) break;
            }
            if (i0 < 0) break;
            int nb = i0 + 1;                // reset lands at nb
            if (nb >= NELEM) break;
            double2 pb = ws->pq[nb];        // uniform address -> broadcast
            Qr = pb.y;
            if (lane == 0) { ws->gbnd[nseg] = nb; ws->gbndQ[nseg] = Qr; }
            nseg++;
            pos = nb + 1;
        }
        if (lane == 0) ws->gnseg = nseg;
    }
    __threadfence();
    grid.sync();   // [7]

    // ================= Phase F: parallel fill (coalesced) =================
    if (live) {
        const int nseg = ws->gnseg;
        int lo = 0, hi = nseg - 1;
        while (lo < hi) {
            int mid = (lo + hi + 1) >> 1;
            if (ws->gbnd[mid] <= idx) lo = mid; else hi = mid - 1;
        }
        if (idx == ws->gbnd[lo]) {
            out[idx] = 0.0f;
        } else {
            double Qr = ws->gbndQ[lo];
            out[idx] = (float)(P * (Q - Qr));   // identical expr/data as search
        }
    }
}

extern "C" void kernel_launch(void* const* d_in, const int* in_sizes, int n_in,
                              void* d_out, int out_size, void* d_ws, size_t ws_size,
                              hipStream_t stream) {
    const float* spikes = (const float*)d_in[0];
    const float* w      = (const float*)d_in[1];
    const float* vrev   = (const float*)d_in[2];
    float* out = (float*)d_out;
    WS* ws = (WS*)d_ws;

    void* args[] = { (void*)&spikes, (void*)&w, (void*)&vrev, (void*)&out, (void*)&ws };
    hipLaunchCooperativeKernel((const void*)k_fused, dim3(NB), dim3(T),
                               args, 0, stream);
}

// Round 5
// 206.290 us; speedup vs baseline: 4.4021x; 4.4021x over previous
//
#include <hip/hip_runtime.h>
#include <cmath>

namespace {
constexpr int NELEM  = 50000;
constexpr int NSYN   = 500;
constexpr int NQ4    = 125;                 // NSYN/4
constexpr int T      = 1024;
constexpr int SBLK   = 49;                  // 49*1024 = 50176 >= NELEM
constexpr int SLOTS  = SBLK * T;            // 50176
constexpr int CMAXC  = (NELEM - 1) >> 6;    // 781 (64-elem chunks)
constexpr int NCH_PAD = 784;
constexpr int MAXSEG = 4096;
constexpr int NGRP   = NELEM / 8;           // 6250
constexpr double DELTA_D = 1.0e-3;
constexpr double THETA_D = 1.0;
constexpr float  DECAY_F = 0.90483741803595957311f;  // float32(exp(-1/10))
}

struct WS {
    double2 pq[SLOTS];                        // (P,Q) entering element i
    double  eAm[SLOTS], eAg[SLOTS], eAi[SLOTS];  // block-exclusive affine entries
    double  ePl[SLOTS], eQl[SLOTS];              // block-exclusive (p,q) entries
    double  rarr[SLOTS];                         // R_i = Q_i - theta/P_i (contiguous!)
    double  gAm[64], gAg[64], gAi[64];           // 49 block aggregates (affine)
    double  gEm[64], gEg[64], gEi[64];           // their exclusive entries
    double  gPp[64], gPq[64];                    // 49 block aggregates (p,q)
    double  gEp[64], gEq[64];                    // their exclusive entries
    double  gmaxR[1024];                         // per-64-chunk max R
    double  gbndQ[MAXSEG];
    int     gbnd[MAXSEG];
    int     gnseg;
    int     pad;
    float   swv[SLOTS];
    float   iwv[SLOTS];
};  // ~3.7 MB

// ---------------- K1: per-timestep weighted row sums (natural layout) ----------------
__global__ __launch_bounds__(256) void k_rowdot(
    const float* __restrict__ spikes,
    const float* __restrict__ w,
    const float* __restrict__ vrev,
    float* __restrict__ swv,
    float* __restrict__ iwv)
{
    const int lane = threadIdx.x & 63;
    const int wv   = threadIdx.x >> 6;
    const int rg   = blockIdx.x * 4 + wv;
    if (rg >= NGRP) return;
    const int row0 = rg * 8;

    const float4* __restrict__ w4 = reinterpret_cast<const float4*>(w);
    const float4* __restrict__ r4 = reinterpret_cast<const float4*>(vrev);
    const int j1 = lane;
    const int j2 = lane + 64;
    const bool has2 = (j2 < NQ4);
    float4 a1 = w4[j1], r1 = r4[j1];
    float4 aw1 = make_float4(fabsf(a1.x), fabsf(a1.y), fabsf(a1.z), fabsf(a1.w));
    float4 ar1 = make_float4(aw1.x * r1.x, aw1.y * r1.y, aw1.z * r1.z, aw1.w * r1.w);
    float4 aw2 = make_float4(0.f, 0.f, 0.f, 0.f), ar2 = aw2;
    if (has2) {
        float4 a2 = w4[j2], r2 = r4[j2];
        aw2 = make_float4(fabsf(a2.x), fabsf(a2.y), fabsf(a2.z), fabsf(a2.w));
        ar2 = make_float4(aw2.x * r2.x, aw2.y * r2.y, aw2.z * r2.z, aw2.w * r2.w);
    }

    float sp[8], ip[8];
#pragma unroll
    for (int r = 0; r < 8; ++r) {
        const float4* __restrict__ srow =
            reinterpret_cast<const float4*>(spikes + (size_t)(row0 + r) * NSYN);
        float4 s1 = srow[j1];
        float a = s1.x * aw1.x + s1.y * aw1.y + s1.z * aw1.z + s1.w * aw1.w;
        float b = s1.x * ar1.x + s1.y * ar1.y + s1.z * ar1.z + s1.w * ar1.w;
        if (has2) {
            float4 s2 = srow[j2];
            a += s2.x * aw2.x + s2.y * aw2.y + s2.z * aw2.z + s2.w * aw2.w;
            b += s2.x * ar2.x + s2.y * ar2.y + s2.z * ar2.z + s2.w * ar2.w;
        }
        sp[r] = a; ip[r] = b;
    }
#pragma unroll
    for (int d = 32; d > 0; d >>= 1) {
#pragma unroll
        for (int r = 0; r < 8; ++r) {
            sp[r] += __shfl_xor(sp[r], d);
            ip[r] += __shfl_xor(ip[r], d);
        }
    }
    if (lane == 0) {
        *reinterpret_cast<float4*>(swv + row0)     = make_float4(sp[0], sp[1], sp[2], sp[3]);
        *reinterpret_cast<float4*>(swv + row0 + 4) = make_float4(sp[4], sp[5], sp[6], sp[7]);
        *reinterpret_cast<float4*>(iwv + row0)     = make_float4(ip[0], ip[1], ip[2], ip[3]);
        *reinterpret_cast<float4*>(iwv + row0 + 4) = make_float4(ip[4], ip[5], ip[6], ip[7]);
    }
}

// ---------------- K2a: block-local affine (m,g,i) scan, 49 blocks ----------------
__global__ __launch_bounds__(1024) void k_scanA(const float* __restrict__ swv,
                                                const float* __restrict__ iwv,
                                                WS* __restrict__ ws)
{
    const int tid = threadIdx.x, lane = tid & 63, wv = tid >> 6, blk = blockIdx.x;
    const int idx = blk * T + tid;
    const bool live = (idx < NELEM);
    const double decay = (double)DECAY_F;
    __shared__ double s_a[16], s_b[16], s_c[16];

    double s = live ? (double)swv[idx] : 0.0;
    double t = live ? (double)iwv[idx] : 0.0;
    double m_in = live ? decay : 1.0;
    double g_in = live ? s * decay : 0.0;
    double i_in = live ? t * decay : 0.0;
#pragma unroll
    for (int d = 1; d < 64; d <<= 1) {
        double pm = __shfl_up(m_in, d);
        double pg = __shfl_up(g_in, d);
        double pi = __shfl_up(i_in, d);
        if (lane >= d) {
            g_in = m_in * pg + g_in;
            i_in = m_in * pi + i_in;
            m_in = pm * m_in;
        }
    }
    if (lane == 63) { s_a[wv] = m_in; s_b[wv] = g_in; s_c[wv] = i_in; }
    __syncthreads();
    if (wv == 0) {
        double wm = (lane < 16) ? s_a[lane] : 1.0;
        double wg = (lane < 16) ? s_b[lane] : 0.0;
        double wi = (lane < 16) ? s_c[lane] : 0.0;
#pragma unroll
        for (int d = 1; d < 16; d <<= 1) {
            double pm = __shfl_up(wm, d);
            double pg = __shfl_up(wg, d);
            double pi = __shfl_up(wi, d);
            if (lane >= d) {
                wg = wm * pg + wg;
                wi = wm * pi + wi;
                wm = pm * wm;
            }
        }
        if (lane < 16) { s_a[lane] = wm; s_b[lane] = wg; s_c[lane] = wi; }
        if (lane == 15) { ws->gAm[blk] = wm; ws->gAg[blk] = wg; ws->gAi[blk] = wi; }
    }
    __syncthreads();
    double em = __shfl_up(m_in, 1), eg = __shfl_up(g_in, 1), ei = __shfl_up(i_in, 1);
    if (lane == 0) { em = 1.0; eg = 0.0; ei = 0.0; }
    if (wv > 0) {
        double qm = s_a[wv - 1], qg = s_b[wv - 1], qi = s_c[wv - 1];
        eg = em * qg + eg;
        ei = em * qi + ei;
        em = qm * em;
    }
    ws->eAm[idx] = em; ws->eAg[idx] = eg; ws->eAi[idx] = ei;
}

// ---------------- K2b: scan 49 affine block aggregates (1 wave) ----------------
__global__ void k_aggA(WS* __restrict__ ws)
{
    const int lane = threadIdx.x;
    double am = (lane < SBLK) ? ws->gAm[lane] : 1.0;
    double ag = (lane < SBLK) ? ws->gAg[lane] : 0.0;
    double ai = (lane < SBLK) ? ws->gAi[lane] : 0.0;
#pragma unroll
    for (int d = 1; d < 64; d <<= 1) {
        double pm = __shfl_up(am, d);
        double pg = __shfl_up(ag, d);
        double pi = __shfl_up(ai, d);
        if (lane >= d) {
            ag = am * pg + ag;
            ai = am * pi + ai;
            am = pm * am;
        }
    }
    double em = __shfl_up(am, 1), eg = __shfl_up(ag, 1), ei = __shfl_up(ai, 1);
    if (lane == 0) { em = 1.0; eg = 0.0; ei = 0.0; }
    if (lane < SBLK) { ws->gEm[lane] = em; ws->gEg[lane] = eg; ws->gEi[lane] = ei; }
}

// ---------------- K2c: (p,q) element values + block-local scan ----------------
__global__ __launch_bounds__(1024) void k_scanB(WS* __restrict__ ws)
{
    const int tid = threadIdx.x, lane = tid & 63, wv = tid >> 6, blk = blockIdx.x;
    const int idx = blk * T + tid;
    const bool live = (idx < NELEM);
    __shared__ double s_a[16], s_b[16];

    double em = ws->eAm[idx], eg = ws->eAg[idx], ei = ws->eAi[idx];
    double qm = ws->gEm[blk], qg = ws->gEg[blk], qi = ws->gEi[blk];
    double Eg = em * qg + eg;            // global-exclusive exp traces entering idx
    double Ei = em * qi + ei;
    (void)qm;

    double p_in = 1.0, q_in = 0.0;
    if (live) {
        double aa = DELTA_D * (1.0 + Eg);
        double om = 1.0 - aa;
        p_in = om;
        q_in = (DELTA_D * Ei) / om;
    }
#pragma unroll
    for (int d = 1; d < 64; d <<= 1) {
        double pp = __shfl_up(p_in, d);
        double pq = __shfl_up(q_in, d);
        if (lane >= d) {
            q_in = pq + q_in / pp;
            p_in = pp * p_in;
        }
    }
    if (lane == 63) { s_a[wv] = p_in; s_b[wv] = q_in; }
    __syncthreads();
    if (wv == 0) {
        double wp = (lane < 16) ? s_a[lane] : 1.0;
        double wq = (lane < 16) ? s_b[lane] : 0.0;
#pragma unroll
        for (int d = 1; d < 16; d <<= 1) {
            double pp = __shfl_up(wp, d);
            double pq = __shfl_up(wq, d);
            if (lane >= d) {
                wq = pq + wq / pp;
                wp = pp * wp;
            }
        }
        if (lane < 16) { s_a[lane] = wp; s_b[lane] = wq; }
        if (lane == 15) { ws->gPp[blk] = wp; ws->gPq[blk] = wq; }
    }
    __syncthreads();
    double ep = __shfl_up(p_in, 1), eq = __shfl_up(q_in, 1);
    if (lane == 0) { ep = 1.0; eq = 0.0; }
    if (wv > 0) {
        double ap = s_a[wv - 1], aq = s_b[wv - 1];
        eq = aq + eq / ap;
        ep = ap * ep;
    }
    ws->ePl[idx] = ep; ws->eQl[idx] = eq;
}

// ---------------- K2d: scan 49 (p,q) block aggregates (1 wave) ----------------
__global__ void k_aggB(WS* __restrict__ ws)
{
    const int lane = threadIdx.x;
    double ap = (lane < SBLK) ? ws->gPp[lane] : 1.0;
    double aq = (lane < SBLK) ? ws->gPq[lane] : 0.0;
#pragma unroll
    for (int d = 1; d < 64; d <<= 1) {
        double pp = __shfl_up(ap, d);
        double pq = __shfl_up(aq, d);
        if (lane >= d) {
            aq = pq + aq / pp;
            ap = pp * ap;
        }
    }
    double ep = __shfl_up(ap, 1), eq = __shfl_up(aq, 1);
    if (lane == 0) { ep = 1.0; eq = 0.0; }
    if (lane < SBLK) { ws->gEp[lane] = ep; ws->gEq[lane] = eq; }
}

// ---------------- K2e: apply -> (P,Q), R array, chunk maxima ----------------
__global__ __launch_bounds__(1024) void k_apply(WS* __restrict__ ws)
{
    const int tid = threadIdx.x, lane = tid & 63, blk = blockIdx.x;
    const int idx = blk * T + tid;
    const bool live = (idx < NELEM);

    double pl = ws->ePl[idx], ql = ws->eQl[idx];
    double ap = ws->gEp[blk], aq = ws->gEq[blk];
    double Q = aq + ql / ap;
    double P = ap * pl;
    ws->pq[idx] = make_double2(P, Q);
    double R = live ? (Q - THETA_D / P) : -1.0e308;
    ws->rarr[idx] = R;
    double mR = R;
#pragma unroll
    for (int d = 32; d > 0; d >>= 1) mR = fmax(mR, __shfl_xor(mR, d));
    if (lane == 0) ws->gmaxR[idx >> 6] = mR;
}

// ---------------- K3: serial segment search (1 block; LDS maxima + L2-warm probes) ----------------
__global__ __launch_bounds__(1024) void k_search(WS* __restrict__ ws)
{
    const int tid = threadIdx.x;
    __shared__ double smax[NCH_PAD];
    __shared__ double s_guard;

    for (int c = tid; c < NCH_PAD; c += T)
        smax[c] = (c <= CMAXC) ? ws->gmaxR[c] : -1.0e308;
    // prewarm rarr + pq into this CU's L2 (turn probe misses into L2 hits)
    double acc = 0.0;
    for (int i = tid; i < NELEM; i += T) acc += ws->rarr[i];
    for (int i = tid; i < NELEM; i += T) acc += ws->pq[i].y;
    if (acc == -1.2345e300) s_guard = acc;   // never true; keeps loads live
    __syncthreads();

    if (tid < 64) {
        const int lane = tid;
        int nseg = 1;
        if (lane == 0) { ws->gbnd[0] = 0; ws->gbndQ[0] = 0.0; }
        double Qr = 0.0;
        int pos = 1;
        while (pos < NELEM && nseg < MAXSEG) {
            int c = pos >> 6;
            int i0 = -1;
            while (true) {
                int cf = -1;
                for (int cb = c; cb <= CMAXC; cb += 64) {
                    int cc = cb + lane;
                    bool qy = (cc <= CMAXC) && (smax[cc] >= Qr);
                    unsigned long long m = __ballot(qy);
                    if (m) { cf = cb + __builtin_ctzll(m); break; }
                }
                if (cf < 0) break;
                int i = (cf << 6) + lane;
                bool valid = (i >= pos) && (i < NELEM);
                double rv = valid ? ws->rarr[i] : -1.0e308;   // coalesced 512B
                unsigned long long m2 = __ballot(valid && (rv >= Qr));
                if (m2) { i0 = (cf << 6) + __builtin_ctzll(m2); break; }
                c = cf + 1;               // chunk max came from masked-out elems
                if (c > CMAXC) break;
            }
            if (i0 < 0) break;
            int nb = i0 + 1;              // reset lands at nb
            if (nb >= NELEM) break;
            Qr = ws->pq[nb].y;            // uniform -> broadcast, L2-warm
            if (lane == 0) { ws->gbnd[nseg] = nb; ws->gbndQ[nseg] = Qr; }
            nseg++;
            pos = nb + 1;
        }
        if (lane == 0) ws->gnseg = nseg;
    }
}

// ---------------- K4: parallel fill ----------------
__global__ __launch_bounds__(1024) void k_fill(const WS* __restrict__ ws,
                                               float* __restrict__ out)
{
    __shared__ int    sb[MAXSEG];
    __shared__ double sq[MAXSEG];
    __shared__ int    s_nseg;
    const int tid = threadIdx.x;
    if (tid == 0) s_nseg = ws->gnseg;
    __syncthreads();
    const int nseg = s_nseg;
    for (int i = tid; i < nseg; i += T) { sb[i] = ws->gbnd[i]; sq[i] = ws->gbndQ[i]; }
    __syncthreads();

    const int idx = blockIdx.x * T + tid;
    if (idx < NELEM) {
        int lo = 0, hi = nseg - 1;
        while (lo < hi) {
            int mid = (lo + hi + 1) >> 1;
            if (sb[mid] <= idx) lo = mid; else hi = mid - 1;
        }
        if (idx == sb[lo]) {
            out[idx] = 0.0f;
        } else {
            double2 pl = ws->pq[idx];
            out[idx] = (float)(pl.x * (pl.y - sq[lo]));
        }
    }
}

extern "C" void kernel_launch(void* const* d_in, const int* in_sizes, int n_in,
                              void* d_out, int out_size, void* d_ws, size_t ws_size,
                              hipStream_t stream) {
    const float* spikes = (const float*)d_in[0];
    const float* w      = (const float*)d_in[1];
    const float* vrev   = (const float*)d_in[2];
    float* out = (float*)d_out;
    WS* ws = (WS*)d_ws;

    hipLaunchKernelGGL(k_rowdot, dim3((NGRP + 3) / 4), dim3(256), 0, stream,
                       spikes, w, vrev, ws->swv, ws->iwv);
    hipLaunchKernelGGL(k_scanA,  dim3(SBLK), dim3(T),  0, stream, ws->swv, ws->iwv, ws);
    hipLaunchKernelGGL(k_aggA,   dim3(1),    dim3(64), 0, stream, ws);
    hipLaunchKernelGGL(k_scanB,  dim3(SBLK), dim3(T),  0, stream, ws);
    hipLaunchKernelGGL(k_aggB,   dim3(1),    dim3(64), 0, stream, ws);
    hipLaunchKernelGGL(k_apply,  dim3(SBLK), dim3(T),  0, stream, ws);
    hipLaunchKernelGGL(k_search, dim3(1),    dim3(T),  0, stream, ws);
    hipLaunchKernelGGL(k_fill,   dim3(SBLK), dim3(T),  0, stream, ws, out);
}